// Round 6
// baseline (934.922 us; speedup 1.0000x reference)
//
#include <hip/hip_runtime.h>

#define BB 512
#define TT 256

typedef __attribute__((ext_vector_type(8)))  short bf8;   // 8 bf16 in 4 VGPRs
typedef __attribute__((ext_vector_type(4)))  short bf4;
typedef __attribute__((ext_vector_type(16))) float f16v;  // MFMA 32x32 acc
typedef __attribute__((ext_vector_type(4)))  float f4v;

#define MFMA(a,b,c) __builtin_amdgcn_mfma_f32_32x32x16_bf16((a),(b),(c),0,0,0)

static __device__ __forceinline__ unsigned short f2bf_rne(float x) {
    unsigned u = __builtin_bit_cast(unsigned, x);
    return (unsigned short)((u + 0x7FFFu + ((u >> 16) & 1u)) >> 16);
}
static __device__ __forceinline__ float bf2f(unsigned short h) {
    unsigned u = ((unsigned)h) << 16;
    return __builtin_bit_cast(float, u);
}
// truncation-based hi/lo split: |x - (hi+lo)| <~ 2^-17 |x|
static __device__ __forceinline__ void tsplit(float x, short& hi, short& lo) {
    unsigned u = __builtin_bit_cast(unsigned, x);
    hi = (short)(u >> 16);
    float hf = __builtin_bit_cast(float, u & 0xFFFF0000u);
    float l  = x - hf;
    lo = (short)(__builtin_bit_cast(unsigned, l) >> 16);
}
static __device__ __forceinline__ bf8 ld8(const unsigned short* p) {
    bf4 a = *(const bf4*)p;
    bf4 b = *(const bf4*)(p + 4);
    bf8 r;
    r[0]=a[0]; r[1]=a[1]; r[2]=a[2]; r[3]=a[3];
    r[4]=b[0]; r[5]=b[1]; r[6]=b[2]; r[7]=b[3];
    return r;
}

// Build the B-fragment (hi/lo bf16) of a 32x32 matrix held in C-layout regs.
// C-layout: lane (c,h) reg r holds M[(r&3)+8(r>>2)+4h][c] (column c).
// B-frag:   lane (c,h) kk needs M[16kk+8h+j][c] — same column, rows re-shuffled:
// exchange with lane^32 and select. (For symmetric M this is also the A-frag.)
static __device__ __forceinline__ void mk_bfrag(const f16v M, int h, bf8 Bh[2], bf8 Bl[2]) {
    float p2[16];
    #pragma unroll
    for (int r = 0; r < 16; ++r) p2[r] = __shfl_xor(M[r], 32, 64);
    float fr[2][8];
    #pragma unroll
    for (int j = 0; j < 4; ++j) {
        fr[0][j]   = h ? p2[4+j]  : M[j];
        fr[0][4+j] = h ? M[4+j]   : p2[j];
        fr[1][j]   = h ? p2[12+j] : M[8+j];
        fr[1][4+j] = h ? M[12+j]  : p2[8+j];
    }
    #pragma unroll
    for (int kk = 0; kk < 2; ++kk)
        #pragma unroll
        for (int j = 0; j < 8; ++j) {
            short hi, lo;
            tsplit(fr[kk][j], hi, lo);
            Bh[kk][j] = hi;
            Bl[kk][j] = lo;
        }
}

// Cramer 4x4 inverse (redundant per lane) -> nG = -(W*Sinv) for this lane's W row.
static __device__ __forceinline__ void gain4(const float* sSp, const float W[4], float nG[4]) {
    f4v q0 = *(const f4v*)&sSp[0];
    f4v q1 = *(const f4v*)&sSp[4];
    f4v q2 = *(const f4v*)&sSp[8];
    f4v q3 = *(const f4v*)&sSp[12];
    const float S0=q0.x,  S1=q1.x,  S2=q2.x,  S3=q3.x;
    const float S4=q0.y,  S5=q1.y,  S6=q2.y,  S7=q3.y;
    const float S8=q0.z,  S9=q1.z,  S10=q2.z, S11=q3.z;
    const float S12=q0.w, S13=q1.w, S14=q2.w, S15=q3.w;

    const float A2323 = S10*S15 - S11*S14;
    const float A1323 = S9 *S15 - S11*S13;
    const float A1223 = S9 *S14 - S10*S13;
    const float A0323 = S8 *S15 - S11*S12;
    const float A0223 = S8 *S14 - S10*S12;
    const float A0123 = S8 *S13 - S9 *S12;
    const float A2313 = S6 *S15 - S7 *S14;
    const float A1313 = S5 *S15 - S7 *S13;
    const float A1213 = S5 *S14 - S6 *S13;
    const float A2312 = S6 *S11 - S7 *S10;
    const float A1312 = S5 *S11 - S7 *S9;
    const float A1212 = S5 *S10 - S6 *S9;
    const float A0313 = S4 *S15 - S7 *S12;
    const float A0213 = S4 *S14 - S6 *S12;
    const float A0312 = S4 *S11 - S7 *S8;
    const float A0212 = S4 *S10 - S6 *S8;
    const float A0113 = S4 *S13 - S5 *S12;
    const float A0112 = S4 *S9  - S5 *S8;

    const float i00 =  (S5*A2323 - S6*A1323 + S7*A1223);
    const float i10 = -(S4*A2323 - S6*A0323 + S7*A0223);
    const float i20 =  (S4*A1323 - S5*A0323 + S7*A0123);
    const float i30 = -(S4*A1223 - S5*A0223 + S6*A0123);
    const float i01 = -(S1*A2323 - S2*A1323 + S3*A1223);
    const float i11 =  (S0*A2323 - S2*A0323 + S3*A0223);
    const float i21 = -(S0*A1323 - S1*A0323 + S3*A0123);
    const float i31 =  (S0*A1223 - S1*A0223 + S2*A0123);
    const float i02 =  (S1*A2313 - S2*A1313 + S3*A1213);
    const float i12 = -(S0*A2313 - S2*A0313 + S3*A0213);
    const float i22 =  (S0*A1313 - S1*A0313 + S3*A0113);
    const float i32 = -(S0*A1213 - S1*A0213 + S2*A0113);
    const float i03 = -(S1*A2312 - S2*A1312 + S3*A1212);
    const float i13 =  (S0*A2312 - S2*A0312 + S3*A0212);
    const float i23 = -(S0*A1312 - S1*A0312 + S3*A0112);
    const float i33 =  (S0*A1212 - S1*A0212 + S2*A0112);

    const float det = S0*i00 + S1*i10 + S2*i20 + S3*i30;
    const float nid = -1.0f / det;

    nG[0] = nid * (W[0]*i00 + W[1]*i10 + W[2]*i20 + W[3]*i30);
    nG[1] = nid * (W[0]*i01 + W[1]*i11 + W[2]*i21 + W[3]*i31);
    nG[2] = nid * (W[0]*i02 + W[1]*i12 + W[2]*i22 + W[3]*i32);
    nG[3] = nid * (W[0]*i03 + W[1]*i13 + W[2]*i23 + W[3]*i33);
}

// TWO chains per wave (256 blocks x 64 thr = 1 wave/CU): the chains' dependency
// stalls fill each other's issue bubbles. No __syncthreads anywhere (single wave,
// in-order ds ops + lgkmcnt give producer->consumer ordering).
// Step: P_p = (F P F^T + Q) - W Sinv W^T,  W = F P H^T.
__global__ __launch_bounds__(64, 1)
void kalman_v6(const float* __restrict__ obs,
               const float* __restrict__ Fg,
               const float* __restrict__ Qg,
               const float* __restrict__ Hg,
               const float* __restrict__ Rg,
               const float* __restrict__ im,
               const float* __restrict__ ic,
               float* __restrict__ out)
{
    __shared__ __align__(16) float sFH[36*40];                        // F rows 0-31, H rows 32-35
    __shared__ __align__(16) unsigned short sPNh[2][4*36], sPNl[2][4*36]; // [n][k]=PHt[k][n]
    __shared__ __align__(16) float sS[2][16];
    __shared__ __align__(16) float sRes[2][4];
    __shared__ __align__(16) float smv[2][32];

    const int lane = threadIdx.x;
    const int c    = lane & 31;
    const int h    = lane >> 5;
    const int b0   = blockIdx.x * 2, b1 = b0 + 1;

    // ---- shared constant fragments: F, H (RNE hi/lo) ----
    bf8 Fh[2], Fl[2], Hh[2], Hl[2];
    #pragma unroll
    for (int kk = 0; kk < 2; ++kk) {
        #pragma unroll
        for (int j = 0; j < 8; ++j) {
            int k = kk*16 + h*8 + j;
            float f = Fg[c*32 + k];
            unsigned short fh = f2bf_rne(f);
            Fh[kk][j] = (short)fh;
            Fl[kk][j] = (short)f2bf_rne(f - bf2f(fh));
            float hv = (c < 4) ? Hg[c*32 + k] : 0.f;
            unsigned short hh = f2bf_rne(hv);
            Hh[kk][j] = (short)hh;
            Hl[kk][j] = (short)f2bf_rne(hv - bf2f(hh));
        }
    }

    f16v Qc, P0, P1;
    #pragma unroll
    for (int reg = 0; reg < 16; ++reg) {
        int row = (reg & 3) + 8*(reg >> 2) + 4*h;
        Qc[reg] = Qg[row*32 + c];
        P0[reg] = ic[(size_t)b0*1024 + row*32 + c];
        P1[reg] = ic[(size_t)b1*1024 + row*32 + c];
    }
    float Rc[4] = {0.f, 0.f, 0.f, 0.f};
    if (c < 4) {
        #pragma unroll
        for (int m = 0; m < 4; ++m) Rc[m] = Rg[m*4 + c];
    }

    #pragma unroll
    for (int e = lane; e < 1024; e += 64) sFH[(e >> 5)*40 + (e & 31)] = Fg[e];
    #pragma unroll
    for (int e = lane; e < 128; e += 64) sFH[(32 + (e >> 5))*40 + (e & 31)] = Hg[e];
    if (lane < 32) {
        smv[0][lane] = im[b0*32 + lane];
        smv[1][lane] = im[b1*32 + lane];
    }

    const float* dotrow = &sFH[(lane < 32 ? lane : (32 + (lane & 3))) * 40];
    const bool yl = (lane >= 32 && lane < 36);
    const float* op0 = obs + (size_t)b0*TT*4 + (yl ? (lane - 32) : 0);
    const float* op1 = obs + (size_t)b1*TT*4 + (yl ? (lane - 32) : 0);
    float* om = out;
    float* oc = out + (size_t)TT * BB * 4;

    float y0 = yl ? op0[0] : 0.f;
    float y1 = yl ? op1[0] : 0.f;

    for (int t = 0; t < TT; ++t) {
        float y0n = (yl && t + 1 < TT) ? op0[(t + 1) * 4] : 0.f;
        float y1n = (yl && t + 1 < TT) ? op1[(t + 1) * 4] : 0.f;

        // lanes<32: Fm[lane]; lanes>=32: mm[lane&3]  (dotrow loads shared)
        float dot0 = 0.f, dot1 = 0.f;
        #pragma unroll
        for (int q = 0; q < 8; ++q) {
            f4v a  = *(const f4v*)&dotrow[4*q];
            f4v m0 = *(const f4v*)&smv[0][4*q];
            f4v m1 = *(const f4v*)&smv[1][4*q];
            dot0 += a.x*m0.x + a.y*m0.y + a.z*m0.z + a.w*m0.w;
            dot1 += a.x*m1.x + a.y*m1.y + a.z*m1.z + a.w*m1.w;
        }

        // ==== group 1 (both chains): T1 = P*F^T,  HP = H*P ====
        bf8 Ph[2], Pl[2], Qh[2], Ql[2];
        mk_bfrag(P0, h, Ph, Pl);
        mk_bfrag(P1, h, Qh, Ql);

        f16v t0A=0.0f, t0B=0.0f, a0A=0.0f, a0B=0.0f;
        t0A=MFMA(Ph[0],Fh[0],t0A);  t0B=MFMA(Ph[1],Fh[1],t0B);
        t0A=MFMA(Ph[0],Fl[0],t0A);  t0B=MFMA(Ph[1],Fl[1],t0B);
        t0A=MFMA(Pl[0],Fh[0],t0A);  t0B=MFMA(Pl[1],Fh[1],t0B);
        a0A=MFMA(Hh[0],Ph[0],a0A);  a0B=MFMA(Hh[1],Ph[1],a0B);
        a0A=MFMA(Hh[0],Pl[0],a0A);  a0B=MFMA(Hh[1],Pl[1],a0B);
        a0A=MFMA(Hl[0],Ph[0],a0A);  a0B=MFMA(Hl[1],Ph[1],a0B);

        f16v t1A=0.0f, t1B=0.0f, a1A=0.0f, a1B=0.0f;
        t1A=MFMA(Qh[0],Fh[0],t1A);  t1B=MFMA(Qh[1],Fh[1],t1B);
        t1A=MFMA(Qh[0],Fl[0],t1A);  t1B=MFMA(Qh[1],Fl[1],t1B);
        t1A=MFMA(Ql[0],Fh[0],t1A);  t1B=MFMA(Ql[1],Fh[1],t1B);
        a1A=MFMA(Hh[0],Qh[0],a1A);  a1B=MFMA(Hh[1],Qh[1],a1B);
        a1A=MFMA(Hh[0],Ql[0],a1A);  a1B=MFMA(Hh[1],Ql[1],a1B);
        a1A=MFMA(Hl[0],Qh[0],a1A);  a1B=MFMA(Hl[1],Qh[1],a1B);

        // PHt scatter (lanes h==0 hold PHt[c][0..3] in regs 0-3)
        if (lane < 32) {
            #pragma unroll
            for (int n = 0; n < 4; ++n) {
                short hi, lo;
                tsplit(a0A[n] + a0B[n], hi, lo);
                sPNh[0][n*36 + c] = (unsigned short)hi;
                sPNl[0][n*36 + c] = (unsigned short)lo;
                tsplit(a1A[n] + a1B[n], hi, lo);
                sPNh[1][n*36 + c] = (unsigned short)hi;
                sPNl[1][n*36 + c] = (unsigned short)lo;
            }
        }

        // T1 B-frags via shfl (no LDS round trip)
        f16v Tp0 = t0A + t0B, Tp1 = t1A + t1B;
        bf8 T0h[2], T0l[2], T1h[2], T1l[2];
        mk_bfrag(Tp0, h, T0h, T0l);
        mk_bfrag(Tp1, h, T1h, T1l);

        // N-frags (B-frag of PHt) from LDS, lanes c<4
        bf8 N0h[2], N0l[2], N1h[2], N1l[2];
        if (c < 4) {
            N0h[0] = ld8(&sPNh[0][c*36 + 8*h]);
            N0h[1] = ld8(&sPNh[0][c*36 + 16 + 8*h]);
            N0l[0] = ld8(&sPNl[0][c*36 + 8*h]);
            N0l[1] = ld8(&sPNl[0][c*36 + 16 + 8*h]);
            N1h[0] = ld8(&sPNh[1][c*36 + 8*h]);
            N1h[1] = ld8(&sPNh[1][c*36 + 16 + 8*h]);
            N1l[0] = ld8(&sPNl[1][c*36 + 8*h]);
            N1l[1] = ld8(&sPNl[1][c*36 + 16 + 8*h]);
        } else {
            #pragma unroll
            for (int kk = 0; kk < 2; ++kk) {
                N0h[kk] = (bf8)(short)0; N0l[kk] = (bf8)(short)0;
                N1h[kk] = (bf8)(short)0; N1l[kk] = (bf8)(short)0;
            }
        }

        // ==== group 2 (both chains): Smeas, W^T, Z ====
        f16v s0A=0.0f, s0B=0.0f, w0A=0.0f, w0B=0.0f, z0A=Qc, z0B=0.0f;
        s0A=MFMA(Hh[0],N0h[0],s0A);  s0B=MFMA(Hh[1],N0h[1],s0B);
        s0A=MFMA(Hh[0],N0l[0],s0A);  s0B=MFMA(Hh[1],N0l[1],s0B);
        s0A=MFMA(Hl[0],N0h[0],s0A);  s0B=MFMA(Hl[1],N0h[1],s0B);
        w0A=MFMA(N0h[0],Fh[0],w0A);  w0B=MFMA(N0h[1],Fh[1],w0B);
        w0A=MFMA(N0h[0],Fl[0],w0A);  w0B=MFMA(N0h[1],Fl[1],w0B);
        w0A=MFMA(N0l[0],Fh[0],w0A);  w0B=MFMA(N0l[1],Fh[1],w0B);
        z0A=MFMA(Fh[0],T0h[0],z0A);  z0B=MFMA(Fh[1],T0h[1],z0B);
        z0A=MFMA(Fh[0],T0l[0],z0A);  z0B=MFMA(Fh[1],T0l[1],z0B);
        z0A=MFMA(Fl[0],T0h[0],z0A);  z0B=MFMA(Fl[1],T0h[1],z0B);

        f16v s1A=0.0f, s1B=0.0f, w1A=0.0f, w1B=0.0f, z1A=Qc, z1B=0.0f;
        s1A=MFMA(Hh[0],N1h[0],s1A);  s1B=MFMA(Hh[1],N1h[1],s1B);
        s1A=MFMA(Hh[0],N1l[0],s1A);  s1B=MFMA(Hh[1],N1l[1],s1B);
        s1A=MFMA(Hl[0],N1h[0],s1A);  s1B=MFMA(Hl[1],N1h[1],s1B);
        w1A=MFMA(N1h[0],Fh[0],w1A);  w1B=MFMA(N1h[1],Fh[1],w1B);
        w1A=MFMA(N1h[0],Fl[0],w1A);  w1B=MFMA(N1h[1],Fl[1],w1B);
        w1A=MFMA(N1l[0],Fh[0],w1A);  w1B=MFMA(N1l[1],Fh[1],w1B);
        z1A=MFMA(Fh[0],T1h[0],z1A);  z1B=MFMA(Fh[1],T1h[1],z1B);
        z1A=MFMA(Fh[0],T1l[0],z1A);  z1B=MFMA(Fh[1],T1l[1],z1B);
        z1A=MFMA(Fl[0],T1h[0],z1A);  z1B=MFMA(Fl[1],T1h[1],z1B);

        // ==== outputs + broadcast staging ====
        float Sm0[4], Sm1[4];
        #pragma unroll
        for (int m = 0; m < 4; ++m) {
            Sm0[m] = s0A[m] + s0B[m] + Rc[m];
            Sm1[m] = s1A[m] + s1B[m] + Rc[m];
        }
        if (lane < 32 && c < 4) {
            #pragma unroll
            for (int m = 0; m < 4; ++m) {
                oc[(((size_t)t*BB + b0)*4 + m)*4 + c] = Sm0[m];
                oc[(((size_t)t*BB + b1)*4 + m)*4 + c] = Sm1[m];
            }
            *(f4v*)&sS[0][c*4] = (f4v){Sm0[0], Sm0[1], Sm0[2], Sm0[3]};
            *(f4v*)&sS[1][c*4] = (f4v){Sm1[0], Sm1[1], Sm1[2], Sm1[3]};
        }
        if (yl) {
            om[((size_t)t*BB + b0)*4 + (lane - 32)] = dot0;
            om[((size_t)t*BB + b1)*4 + (lane - 32)] = dot1;
            sRes[0][lane - 32] = y0 - dot0;
            sRes[1][lane - 32] = y1 - dot1;
        }

        if (t == TT - 1) break;
        y0 = y0n; y1 = y1n;

        // ==== gain + rank-4 correction + mean, chain0 ====
        {
            float W[4] = {w0A[0]+w0B[0], w0A[1]+w0B[1], w0A[2]+w0B[2], w0A[3]+w0B[3]};
            float nG[4];
            gain4(&sS[0][0], W, nG);

            bf8 Gh=(bf8)(short)0, Gl=(bf8)(short)0, Wbh=(bf8)(short)0, Wbl=(bf8)(short)0;
            #pragma unroll
            for (int j = 0; j < 4; ++j) {
                short hi, lo;
                tsplit(nG[j], hi, lo);  Gh[j]=hi;  Gl[j]=lo;
                tsplit(W[j],  hi, lo);  Wbh[j]=hi; Wbl[j]=lo;
            }
            f16v Pn = z0A + z0B;
            Pn = MFMA(Gh, Wbh, Pn);
            Pn = MFMA(Gh, Wbl, Pn);
            Pn = MFMA(Gl, Wbh, Pn);
            P0 = Pn;

            f4v rv = *(const f4v*)&sRes[0][0];
            if (lane < 32)
                smv[0][lane] = dot0 - (nG[0]*rv.x + nG[1]*rv.y + nG[2]*rv.z + nG[3]*rv.w);
        }
        // ==== gain + rank-4 correction + mean, chain1 ====
        {
            float W[4] = {w1A[0]+w1B[0], w1A[1]+w1B[1], w1A[2]+w1B[2], w1A[3]+w1B[3]};
            float nG[4];
            gain4(&sS[1][0], W, nG);

            bf8 Gh=(bf8)(short)0, Gl=(bf8)(short)0, Wbh=(bf8)(short)0, Wbl=(bf8)(short)0;
            #pragma unroll
            for (int j = 0; j < 4; ++j) {
                short hi, lo;
                tsplit(nG[j], hi, lo);  Gh[j]=hi;  Gl[j]=lo;
                tsplit(W[j],  hi, lo);  Wbh[j]=hi; Wbl[j]=lo;
            }
            f16v Pn = z1A + z1B;
            Pn = MFMA(Gh, Wbh, Pn);
            Pn = MFMA(Gh, Wbl, Pn);
            Pn = MFMA(Gl, Wbh, Pn);
            P1 = Pn;

            f4v rv = *(const f4v*)&sRes[1][0];
            if (lane < 32)
                smv[1][lane] = dot1 - (nG[0]*rv.x + nG[1]*rv.y + nG[2]*rv.z + nG[3]*rv.w);
        }
    }
}

extern "C" void kernel_launch(void* const* d_in, const int* in_sizes, int n_in,
                              void* d_out, int out_size, void* d_ws, size_t ws_size,
                              hipStream_t stream) {
    const float* obs       = (const float*)d_in[0];
    const float* F         = (const float*)d_in[1];
    const float* Q         = (const float*)d_in[2];
    const float* H         = (const float*)d_in[3];
    const float* R         = (const float*)d_in[4];
    const float* init_mean = (const float*)d_in[5];
    const float* init_cov  = (const float*)d_in[6];
    float* out = (float*)d_out;

    kalman_v6<<<BB/2, 64, 0, stream>>>(obs, F, Q, H, R, init_mean, init_cov, out);
}

// Round 8
// 563.268 us; speedup vs baseline: 1.6598x; 1.6598x over previous
//
#include <hip/hip_runtime.h>

#define BB 512
#define TT 256
#define PS 40   // PN row stride in halves (80B rows)

typedef __attribute__((ext_vector_type(2)))  _Float16 h2;
typedef __attribute__((ext_vector_type(4)))  _Float16 h4;
typedef __attribute__((ext_vector_type(8)))  _Float16 h8;
typedef __attribute__((ext_vector_type(4)))  unsigned u4v;
typedef __attribute__((ext_vector_type(16))) float f16v;
typedef __attribute__((ext_vector_type(4)))  float f4v;

#define MFMA(a,b,c) __builtin_amdgcn_mfma_f32_32x32x16_f16((a),(b),(c),0,0,0)

// pack-split: one v_cvt_pkrtz for the hi pair, recover, one for the lo pair.
// |x - (hi+lo)| <~ 2^-21 |x|
static __device__ __forceinline__ void pksplit(float x0, float x1, unsigned& hi, unsigned& lo) {
    h2 h = __builtin_bit_cast(h2, __builtin_amdgcn_cvt_pkrtz(x0, x1));
    h2 l = __builtin_bit_cast(h2, __builtin_amdgcn_cvt_pkrtz(x0 - (float)h[0], x1 - (float)h[1]));
    hi = __builtin_bit_cast(unsigned, h);
    lo = __builtin_bit_cast(unsigned, l);
}

// Build A/B-fragment (fp16 hi/lo) of a 32x32 matrix held in C-layout regs.
// C-layout: lane (c,h) reg r holds M[(r&3)+8(r>>2)+4h][c].
// Frag: lane (c,h) kk holds M[16kk+8h+j][c] — split+pack first, shfl packed u32s, select pairs.
static __device__ __forceinline__ void mkfrag(const f16v M, int h, h8 Ah[2], h8 Al[2]) {
    unsigned ph[8], pl[8], xh[8], xl[8];
    #pragma unroll
    for (int q = 0; q < 8; ++q) pksplit(M[2*q], M[2*q+1], ph[q], pl[q]);
    #pragma unroll
    for (int q = 0; q < 8; ++q) {
        xh[q] = (unsigned)__shfl_xor((int)ph[q], 32, 64);
        xl[q] = (unsigned)__shfl_xor((int)pl[q], 32, 64);
    }
    u4v a0h = { h ? xh[2] : ph[0], h ? xh[3] : ph[1], h ? ph[2] : xh[0], h ? ph[3] : xh[1] };
    u4v a1h = { h ? xh[6] : ph[4], h ? xh[7] : ph[5], h ? ph[6] : xh[4], h ? ph[7] : xh[5] };
    u4v a0l = { h ? xl[2] : pl[0], h ? xl[3] : pl[1], h ? pl[2] : xl[0], h ? pl[3] : xl[1] };
    u4v a1l = { h ? xl[6] : pl[4], h ? xl[7] : pl[5], h ? pl[6] : xl[4], h ? pl[7] : xl[5] };
    Ah[0] = __builtin_bit_cast(h8, a0h);  Ah[1] = __builtin_bit_cast(h8, a1h);
    Al[0] = __builtin_bit_cast(h8, a0l);  Al[1] = __builtin_bit_cast(h8, a1l);
}

static __device__ __forceinline__ h8 ld8h(const _Float16* p) {
    h4 a = *(const h4*)p;
    h4 b = *(const h4*)(p + 4);
    h8 r;
    r[0]=a[0]; r[1]=a[1]; r[2]=a[2]; r[3]=a[3];
    r[4]=b[0]; r[5]=b[1]; r[6]=b[2]; r[7]=b[3];
    return r;
}

// One chain per wave (512 blocks x 64 thr). No __syncthreads: single-wave block,
// in-order ds ops + compiler lgkmcnt give producer->consumer ordering.
// Step: P_p = (F P F^T + Q) - W Sinv W^T,  W = F P H^T (Cramer parallel to Z arm).
__global__ __launch_bounds__(64, 1)
void kalman_v7(const float* __restrict__ obs,
               const float* __restrict__ Fg,
               const float* __restrict__ Qg,
               const float* __restrict__ Hg,
               const float* __restrict__ Rg,
               const float* __restrict__ im,
               const float* __restrict__ ic,
               float* __restrict__ out)
{
    __shared__ __align__(16) _Float16 sPNh[4*PS], sPNl[4*PS];  // [n][k] = PHt[k][n]
    __shared__ __align__(16) float sm[32];
    __shared__ __align__(16) float sS[16];     // sS[c*4+m] = Smeas[m][c]
    __shared__ __align__(16) float sRes4[4];

    const int lane = threadIdx.x;
    const int b    = blockIdx.x;
    const int c    = lane & 31;
    const int h    = lane >> 5;

    // ---- constant fragments: F, H (fp16 hi/lo) ----
    h8 Fh[2], Fl[2], Hh[2], Hl[2];
    #pragma unroll
    for (int kk = 0; kk < 2; ++kk) {
        #pragma unroll
        for (int j = 0; j < 8; ++j) {
            int k = kk*16 + h*8 + j;
            float f = Fg[c*32 + k];
            _Float16 fh = (_Float16)f;
            Fh[kk][j] = fh;
            Fl[kk][j] = (_Float16)(f - (float)fh);
            float hv = (c < 4) ? Hg[c*32 + k] : 0.f;
            _Float16 hh = (_Float16)hv;
            Hh[kk][j] = hh;
            Hl[kk][j] = (_Float16)(hv - (float)hh);
        }
    }

    // ---- dot rows in registers: lanes<32 F[lane][:], lanes>=32 H[lane&3][:] ----
    float Frow[32];
    #pragma unroll
    for (int k = 0; k < 32; ++k)
        Frow[k] = (lane < 32) ? Fg[c*32 + k] : Hg[(lane & 3)*32 + k];

    // ---- Q and P in C-layout registers ----
    f16v Qc, P;
    #pragma unroll
    for (int reg = 0; reg < 16; ++reg) {
        int row = (reg & 3) + 8*(reg >> 2) + 4*h;
        Qc[reg] = Qg[row*32 + c];
        P[reg]  = ic[(size_t)b*1024 + row*32 + c];
    }
    float Rc[4] = {0.f, 0.f, 0.f, 0.f};
    if (c < 4) {
        #pragma unroll
        for (int m = 0; m < 4; ++m) Rc[m] = Rg[m*4 + c];
    }
    if (lane < 32) sm[lane] = im[b*32 + lane];

    const bool yl = (lane >= 32 && lane < 36);
    const float* obsp = obs + (size_t)b*TT*4 + (yl ? (lane - 32) : 0);
    float* om = out;
    float* oc = out + (size_t)TT * BB * 4;

    float yv = yl ? obsp[0] : 0.f;

    for (int t = 0; t < TT; ++t) {
        float yv_nxt = (yl && t + 1 < TT) ? obsp[(t + 1) * 4] : 0.f;

        // lanes<32: Fm[lane]; lanes>=32: mm[lane&3]  (sm written at end of prev step)
        float dotv = 0.f;
        #pragma unroll
        for (int q = 0; q < 8; ++q) {
            f4v mv = *(const f4v*)&sm[4*q];
            dotv += Frow[4*q+0]*mv.x + Frow[4*q+1]*mv.y
                  + Frow[4*q+2]*mv.z + Frow[4*q+3]*mv.w;
        }

        // ---- P fragment (P symmetric: B-frag == A-frag) ----
        h8 Ph[2], Pl[2];
        mkfrag(P, h, Ph, Pl);

        // ---- HP = H*P (critical: feeds PN) ----
        f16v aA = 0.0f, aB = 0.0f;
        aA = MFMA(Hh[0], Ph[0], aA);  aB = MFMA(Hh[1], Ph[1], aB);
        aA = MFMA(Hh[0], Pl[0], aA);  aB = MFMA(Hh[1], Pl[1], aB);
        aA = MFMA(Hl[0], Ph[0], aA);  aB = MFMA(Hl[1], Ph[1], aB);

        // scatter PHt rows: sPN[n][k=c]  (lanes h==0 hold PHt[c][0..3] in regs 0-3)
        if (lane < 32) {
            unsigned h01, l01, h23, l23;
            pksplit(aA[0]+aB[0], aA[1]+aB[1], h01, l01);
            pksplit(aA[2]+aB[2], aA[3]+aB[3], h23, l23);
            h2 H01 = __builtin_bit_cast(h2, h01), L01 = __builtin_bit_cast(h2, l01);
            h2 H23 = __builtin_bit_cast(h2, h23), L23 = __builtin_bit_cast(h2, l23);
            sPNh[0*PS + c] = H01[0];  sPNh[1*PS + c] = H01[1];
            sPNh[2*PS + c] = H23[0];  sPNh[3*PS + c] = H23[1];
            sPNl[0*PS + c] = L01[0];  sPNl[1*PS + c] = L01[1];
            sPNl[2*PS + c] = L23[0];  sPNl[3*PS + c] = L23[1];
        }

        // ---- T1 = P*F^T (parallel arm) ----
        f16v tA = 0.0f, tB = 0.0f;
        tA = MFMA(Ph[0], Fh[0], tA);  tB = MFMA(Ph[1], Fh[1], tB);
        tA = MFMA(Ph[0], Fl[0], tA);  tB = MFMA(Ph[1], Fl[1], tB);
        tA = MFMA(Pl[0], Fh[0], tA);  tB = MFMA(Pl[1], Fh[1], tB);

        // ---- N frags (B-frag of PHt) from LDS, lanes c<4 ----
        h8 N0h, N1h, N0l, N1l;
        if (c < 4) {
            N0h = ld8h(&sPNh[c*PS + 8*h]);
            N1h = ld8h(&sPNh[c*PS + 16 + 8*h]);
            N0l = ld8h(&sPNl[c*PS + 8*h]);
            N1l = ld8h(&sPNl[c*PS + 16 + 8*h]);
        } else {
            N0h = (h8)(_Float16)0; N1h = (h8)(_Float16)0;
            N0l = (h8)(_Float16)0; N1l = (h8)(_Float16)0;
        }

        // ---- S = H*PHt + R  and  W^T = PHt^T*F^T  (both from N) ----
        f16v sA = 0.0f, sB = 0.0f;
        sA = MFMA(Hh[0], N0h, sA);  sB = MFMA(Hh[1], N1h, sB);
        sA = MFMA(Hh[0], N0l, sA);  sB = MFMA(Hh[1], N1l, sB);
        sA = MFMA(Hl[0], N0h, sA);  sB = MFMA(Hl[1], N1h, sB);

        f16v wA = 0.0f, wB = 0.0f;
        wA = MFMA(N0h, Fh[0], wA);  wB = MFMA(N1h, Fh[1], wB);
        wA = MFMA(N0h, Fl[0], wA);  wB = MFMA(N1h, Fl[1], wB);
        wA = MFMA(N0l, Fh[0], wA);  wB = MFMA(N1l, Fh[1], wB);

        // ---- T1 fragment + Z = F*T1 + Q ----
        f16v Tp = tA + tB;
        h8 Th[2], Tl[2];
        mkfrag(Tp, h, Th, Tl);

        f16v zA = Qc, zB = 0.0f;
        zA = MFMA(Fh[0], Th[0], zA);  zB = MFMA(Fh[1], Th[1], zB);
        zA = MFMA(Fh[0], Tl[0], zA);  zB = MFMA(Fh[1], Tl[1], zB);
        zA = MFMA(Fl[0], Th[0], zA);  zB = MFMA(Fl[1], Th[1], zB);

        // ---- outputs + broadcast staging ----
        float Smr[4];
        #pragma unroll
        for (int m = 0; m < 4; ++m) Smr[m] = sA[m] + sB[m] + Rc[m];
        if (lane < 32 && c < 4) {
            #pragma unroll
            for (int m = 0; m < 4; ++m)
                oc[(((size_t)t*BB + b)*4 + m)*4 + c] = Smr[m];
            *(f4v*)&sS[c*4] = (f4v){Smr[0], Smr[1], Smr[2], Smr[3]};
        }
        if (yl) {
            om[((size_t)t*BB + b)*4 + (lane - 32)] = dotv;
            sRes4[lane - 32] = yv - dotv;
        }

        if (t == TT - 1) break;
        yv = yv_nxt;

        // ---- Smeas broadcast + Cramer (fp32, redundant per lane) ----
        f4v q0 = *(const f4v*)&sS[0];
        f4v q1 = *(const f4v*)&sS[4];
        f4v q2 = *(const f4v*)&sS[8];
        f4v q3 = *(const f4v*)&sS[12];
        const float S0=q0.x,  S1=q1.x,  S2=q2.x,  S3=q3.x;
        const float S4=q0.y,  S5=q1.y,  S6=q2.y,  S7=q3.y;
        const float S8=q0.z,  S9=q1.z,  S10=q2.z, S11=q3.z;
        const float S12=q0.w, S13=q1.w, S14=q2.w, S15=q3.w;

        float nG0, nG1, nG2, nG3, W0, W1, W2, W3;
        {
            const float A2323 = S10*S15 - S11*S14;
            const float A1323 = S9 *S15 - S11*S13;
            const float A1223 = S9 *S14 - S10*S13;
            const float A0323 = S8 *S15 - S11*S12;
            const float A0223 = S8 *S14 - S10*S12;
            const float A0123 = S8 *S13 - S9 *S12;
            const float A2313 = S6 *S15 - S7 *S14;
            const float A1313 = S5 *S15 - S7 *S13;
            const float A1213 = S5 *S14 - S6 *S13;
            const float A2312 = S6 *S11 - S7 *S10;
            const float A1312 = S5 *S11 - S7 *S9;
            const float A1212 = S5 *S10 - S6 *S9;
            const float A0313 = S4 *S15 - S7 *S12;
            const float A0213 = S4 *S14 - S6 *S12;
            const float A0312 = S4 *S11 - S7 *S8;
            const float A0212 = S4 *S10 - S6 *S8;
            const float A0113 = S4 *S13 - S5 *S12;
            const float A0112 = S4 *S9  - S5 *S8;

            const float i00 =  (S5*A2323 - S6*A1323 + S7*A1223);
            const float i10 = -(S4*A2323 - S6*A0323 + S7*A0223);
            const float i20 =  (S4*A1323 - S5*A0323 + S7*A0123);
            const float i30 = -(S4*A1223 - S5*A0223 + S6*A0123);
            const float i01 = -(S1*A2323 - S2*A1323 + S3*A1223);
            const float i11 =  (S0*A2323 - S2*A0323 + S3*A0223);
            const float i21 = -(S0*A1323 - S1*A0323 + S3*A0123);
            const float i31 =  (S0*A1223 - S1*A0223 + S2*A0123);
            const float i02 =  (S1*A2313 - S2*A1313 + S3*A1213);
            const float i12 = -(S0*A2313 - S2*A0313 + S3*A0213);
            const float i22 =  (S0*A1313 - S1*A0313 + S3*A0113);
            const float i32 = -(S0*A1213 - S1*A0213 + S2*A0113);
            const float i03 = -(S1*A2312 - S2*A1312 + S3*A1212);
            const float i13 =  (S0*A2312 - S2*A0312 + S3*A0212);
            const float i23 = -(S0*A1312 - S1*A0312 + S3*A0112);
            const float i33 =  (S0*A1212 - S1*A0212 + S2*A0112);

            const float det = S0*i00 + S1*i10 + S2*i20 + S3*i30;
            const float nid = -1.0f / det;   // nG = -W*Sinv

            W0 = wA[0] + wB[0];
            W1 = wA[1] + wB[1];
            W2 = wA[2] + wB[2];
            W3 = wA[3] + wB[3];

            nG0 = nid * (W0*i00 + W1*i10 + W2*i20 + W3*i30);
            nG1 = nid * (W0*i01 + W1*i11 + W2*i21 + W3*i31);
            nG2 = nid * (W0*i02 + W1*i12 + W2*i22 + W3*i32);
            nG3 = nid * (W0*i03 + W1*i13 + W2*i23 + W3*i33);
        }

        // ---- rank-4 correction: P_p = Z - W Sinv W^T  (h==1 lanes: W=0 -> nG=0) ----
        h8 Gh8, Gl8, Wh8, Wl8;
        {
            unsigned g01, gl01, g23, gl23, w01, wl01, w23, wl23;
            pksplit(nG0, nG1, g01, gl01);
            pksplit(nG2, nG3, g23, gl23);
            pksplit(W0, W1, w01, wl01);
            pksplit(W2, W3, w23, wl23);
            u4v gh = {g01, g23, 0u, 0u}, gl = {gl01, gl23, 0u, 0u};
            u4v wh = {w01, w23, 0u, 0u}, wl = {wl01, wl23, 0u, 0u};
            Gh8 = __builtin_bit_cast(h8, gh);  Gl8 = __builtin_bit_cast(h8, gl);
            Wh8 = __builtin_bit_cast(h8, wh);  Wl8 = __builtin_bit_cast(h8, wl);
        }
        zA = MFMA(Gh8, Wh8, zA);
        zB = MFMA(Gh8, Wl8, zB);
        zA = MFMA(Gl8, Wh8, zA);
        P = zA + zB;

        // ---- mean: m_next = Fm - nG.resid  (lanes<32; dotv==Fm there) ----
        {
            f4v rv = *(const f4v*)&sRes4[0];
            if (lane < 32)
                sm[lane] = dotv - (nG0*rv.x + nG1*rv.y + nG2*rv.z + nG3*rv.w);
        }
    }
}

extern "C" void kernel_launch(void* const* d_in, const int* in_sizes, int n_in,
                              void* d_out, int out_size, void* d_ws, size_t ws_size,
                              hipStream_t stream) {
    const float* obs       = (const float*)d_in[0];
    const float* F         = (const float*)d_in[1];
    const float* Q         = (const float*)d_in[2];
    const float* H         = (const float*)d_in[3];
    const float* R         = (const float*)d_in[4];
    const float* init_mean = (const float*)d_in[5];
    const float* init_cov  = (const float*)d_in[6];
    float* out = (float*)d_out;

    kalman_v7<<<BB, 64, 0, stream>>>(obs, F, Q, H, R, init_mean, init_cov, out);
}